// Round 11
// baseline (171.314 us; speedup 1.0000x reference)
//
#include <hip/hip_runtime.h>
#include <hip/hip_bf16.h>
#include <stdint.h>

#define D_IN 1024
#define NH 16
#define DH 64
#define SEQ 2048
#define BATCH 2

typedef unsigned short u16;
typedef __attribute__((ext_vector_type(8))) short short8;
typedef __attribute__((ext_vector_type(4))) float f32x4;

#define CSCALE 0.1803368801f   // 0.125 * log2(e), folded into Q

__device__ __forceinline__ u16 f2bf(float f) {
    union { float f; uint32_t u; } v; v.f = f;
    uint32_t r = v.u + 0x7FFF + ((v.u >> 16) & 1);
    return (u16)(r >> 16);
}

// pack two fp32 -> two bf16 (truncate) in ONE v_perm_b32
__device__ __forceinline__ uint32_t pktrunc(float a, float b) {
    union { float f; uint32_t u; } x, y;
    x.f = a; y.f = b;
    return __builtin_amdgcn_perm(y.u, x.u, 0x07060302u);
}

__device__ __forceinline__ void async16(const u16* g, u16* l) {
    __builtin_amdgcn_global_load_lds(
        (const __attribute__((address_space(1))) void*)g,
        (__attribute__((address_space(3))) void*)l, 16, 0, 0);
}

// ---- fused prep: x fp32->bf16 cast (blocks 0..4095) + W transpose/cast ----
__global__ __launch_bounds__(256) void prep_kernel(
    const float* __restrict__ x, const float* __restrict__ Wq,
    const float* __restrict__ Wk, const float* __restrict__ Wv,
    u16* __restrict__ xb, u16* __restrict__ WT)
{
    __shared__ float tile[64][65];
    if (blockIdx.x < 4096) {
        int i = (blockIdx.x * 256 + threadIdx.x) * 4;
        float4 v = *(const float4*)(x + i);
        union { u16 u[4]; uint2 d; } o;
        o.u[0] = f2bf(v.x); o.u[1] = f2bf(v.y); o.u[2] = f2bf(v.z); o.u[3] = f2bf(v.w);
        *(uint2*)(xb + i) = o.d;
        return;
    }
    int idx = blockIdx.x - 4096;
    int mat = idx >> 8, rem = idx & 255;
    int k0 = (rem & 15) * 64, n0 = (rem >> 4) * 64;
    const float* W = (mat == 0) ? Wq : (mat == 1 ? Wk : Wv);
    int c = threadIdx.x & 63, rb = threadIdx.x >> 6;
    #pragma unroll
    for (int p = 0; p < 16; ++p) {
        int r = p * 4 + rb;
        tile[r][c] = W[(size_t)(k0 + r) * 1024 + n0 + c];
    }
    __syncthreads();
    #pragma unroll
    for (int p = 0; p < 16; ++p) {
        int r = p * 4 + rb;
        WT[((size_t)mat * 1024 + n0 + r) * 1024 + k0 + c] = f2bf(tile[c][r]);
    }
}

// ---- fused QKV GEMM: BK=64, XOR-swizzled LDS (conflict-free), V transposed ----
__global__ __launch_bounds__(256) void qkv_gemm_kernel(
    const u16* __restrict__ xb, const u16* __restrict__ WT,
    const float* __restrict__ bq, const float* __restrict__ bk,
    const float* __restrict__ bv,
    u16* __restrict__ Qb, u16* __restrict__ Kb, u16* __restrict__ Vt)
{
    __shared__ u16 smem[4 * 64 * 72];   // 36 KB; k-loop uses 32 KB (As+Bs)
    u16* As = smem;                     // [128][64], chunk-swizzled
    u16* Bs = smem + 128 * 64;
    const int tid  = threadIdx.x;
    const int wave = tid >> 6, lane = tid & 63;
    const int quad = lane >> 4, l15 = lane & 15;
    const int m0 = blockIdx.y * 128;
    const int n0 = blockIdx.x * 128;

    f32x4 acc[4][4];
    #pragma unroll
    for (int i = 0; i < 4; ++i)
        #pragma unroll
        for (int j = 0; j < 4; ++j)
            acc[i][j] = (f32x4){0.f, 0.f, 0.f, 0.f};

    const int wm = wave & 1, wn = wave >> 1;
    const int srow8 = tid >> 3;        // 0..31
    const int sslot = tid & 7;
    const int fsig  = l15 & 7;         // fragment-row swizzle key

    for (int k0 = 0; k0 < 1024; k0 += 64) {
        #pragma unroll
        for (int rnd = 0; rnd < 4; ++rnd) {
            int row = rnd * 32 + srow8;
            int g = sslot ^ (row & 7);
            async16(xb + (size_t)(m0 + row) * 1024 + k0 + g * 8, As + rnd * 2048 + tid * 8);
            async16(WT + (size_t)(n0 + row) * 1024 + k0 + g * 8, Bs + rnd * 2048 + tid * 8);
        }
        __syncthreads();
        #pragma unroll
        for (int kk = 0; kk < 2; ++kk) {
            short8 af[4], bfr[4];
            #pragma unroll
            for (int f = 0; f < 4; ++f) {
                int slot = ((kk << 2) + quad) ^ fsig;
                af[f]  = *(const short8*)(As + (wm * 64 + f * 16 + l15) * 64 + slot * 8);
                bfr[f] = *(const short8*)(Bs + (wn * 64 + f * 16 + l15) * 64 + slot * 8);
            }
            #pragma unroll
            for (int i = 0; i < 4; ++i)
                #pragma unroll
                for (int j = 0; j < 4; ++j)
                    acc[i][j] = __builtin_amdgcn_mfma_f32_16x16x32_bf16(af[i], bfr[j], acc[i][j], 0, 0, 0);
        }
        __syncthreads();
    }

    const int mat = n0 >> 10;
    const int ncb = (n0 & 1023) + wn * 64;   // multiple of 64
    const int hh = ncb >> 6;
    const int bb = m0 >> 11, sb = m0 & 2047;

    if (mat < 2) {
        const float* bias = (mat == 0) ? bq : bk;
        u16* dst = (mat == 0) ? Qb : Kb;
        const float sc = (mat == 0) ? CSCALE : 1.0f;
        #pragma unroll
        for (int i = 0; i < 4; ++i) {
            int ss = sb + wm * 64 + i * 16 + quad * 4;
            #pragma unroll
            for (int j = 0; j < 4; ++j) {
                int dh = j * 16 + l15;
                float bval = bias[ncb + dh];
                size_t base = (((size_t)bb * NH + hh) * SEQ + ss) * DH + dh;
                #pragma unroll
                for (int r = 0; r < 4; ++r)
                    dst[base + (size_t)r * DH] = f2bf((acc[i][j][r] + bval) * sc);
            }
        }
    } else {
        // V: per-wave LDS transpose (smem free after final barrier), b128 stores
        u16* vt = smem + wave * (64 * 72);   // [dh][m], stride 72
        #pragma unroll
        for (int i = 0; i < 4; ++i)
            #pragma unroll
            for (int j = 0; j < 4; ++j) {
                float bval = bv[ncb + j * 16 + l15];
                union { u16 u[4]; uint2 d; } o;
                #pragma unroll
                for (int r = 0; r < 4; ++r)
                    o.u[r] = f2bf(acc[i][j][r] + bval);
                *(uint2*)(vt + (j * 16 + l15) * 72 + i * 16 + quad * 4) = o.d;
            }
        const int s0w = sb + wm * 64;
        u16* vdst = Vt + ((size_t)(bb * NH + hh) * DH) * SEQ;
        #pragma unroll
        for (int it = 0; it < 8; ++it) {
            int dh = it * 8 + (lane >> 3);
            short8 v = *(const short8*)(vt + dh * 72 + (lane & 7) * 8);
            *(short8*)(vdst + (size_t)dh * SEQ + s0w + (lane & 7) * 8) = v;
        }
    }
}

// ---- stage one 64x64 bf16 tile into LDS, swizzle sigma(row)=4*((row>>3)&1)+(row&3) ----
__device__ __forceinline__ void stage64(const u16* g0, size_t gstride, u16* lds,
                                        int w4, int lane)
{
    #pragma unroll
    for (int rnd = 0; rnd < 2; ++rnd) {
        int row = rnd * 32 + w4 * 8 + (lane >> 3);
        int sig = ((row >> 3) & 1) * 4 + (row & 3);
        int c = (lane & 7) ^ sig;
        async16(g0 + (size_t)row * gstride + c * 8, lds + row * 64 + (lane & 7) * 8);
    }
}

// ---- flash attention (causal): one block per (bh, qt of 128 q-rows),
// 512 threads = two 4-wave groups. Group 0 runs key-tiles [0,qt], group 1
// runs [qt+1, 2qt+1] (equal counts -> lockstep barriers). No-max exact
// softmax (p = 2^s, scale in Q); in-lane P via permuted-K QK output;
// l via MFMA-with-ones. Groups merge in LDS at the end: no partials, no
// combine kernel, no extra launch boundary.
__global__ __launch_bounds__(512) void flash_mfma_kernel(
    const u16* __restrict__ Qb, const u16* __restrict__ Kb,
    const u16* __restrict__ Vt, float* __restrict__ out)
{
    __shared__ u16 smem[8 * 4096];   // 64 KB: K[grp][buf] @0, V[grp][buf] @16384

    const int tid  = threadIdx.x;
    const int wave = tid >> 6, lane = tid & 63;
    const int grp  = wave >> 2, w4 = wave & 3;
    const int quad = lane >> 4, l15 = lane & 15;
    const int bhx = blockIdx.x;                 // 0..31
    const int b = bhx >> 4, h = bhx & 15;
    // pair heavy with light: y<8 -> qt=15-y, else qt=y-8 (sum per CU pair = 17)
    const int qt = (blockIdx.y < 8) ? (15 - (int)blockIdx.y) : ((int)blockIdx.y - 8);
    const int q0 = qt * 128;
    const int wq0 = w4 * 32;
    const size_t bh = (size_t)bhx;
    const u16* Qp = Qb + bh * SEQ * DH;
    const u16* Kp = Kb + bh * SEQ * DH;
    const u16* Vp = Vt + bh * DH * SEQ;

    u16* Kg[2] = { smem + (grp * 2 + 0) * 4096, smem + (grp * 2 + 1) * 4096 };
    u16* Vg[2] = { smem + 16384 + (grp * 2 + 0) * 4096, smem + 16384 + (grp * 2 + 1) * 4096 };

    // Q as B-operand fragments (both groups read the same rows; L1 hit)
    short8 qf[2][2];
    #pragma unroll
    for (int qa = 0; qa < 2; ++qa) {
        const u16* qrp = Qp + (size_t)(q0 + wq0 + qa * 16 + l15) * DH;
        qf[qa][0] = *(const short8*)(qrp + quad * 8);
        qf[qa][1] = *(const short8*)(qrp + 32 + quad * 8);
    }

    const short8 ones = (short8){0x3F80, 0x3F80, 0x3F80, 0x3F80,
                                 0x3F80, 0x3F80, 0x3F80, 0x3F80};  // bf16 1.0

    f32x4 O[2][4], L[2];
    #pragma unroll
    for (int pa = 0; pa < 2; ++pa) {
        #pragma unroll
        for (int f = 0; f < 4; ++f) O[pa][f] = (f32x4){0.f, 0.f, 0.f, 0.f};
        L[pa] = (f32x4){0.f, 0.f, 0.f, 0.f};
    }

    const int wqmax = q0 + wq0 + 31;
    const int krbase = (l15 >> 2) * 8 + (l15 & 3);
    const int ksig   = ((l15 >> 2) & 1) * 4 + (l15 & 3);
    const int vsig   = ((l15 >> 3) & 1) * 4 + (l15 & 3);

    const int niter = qt + 1;
    const int tbase = grp ? (qt + 1) : 0;

    stage64(Kp + (size_t)tbase * 64 * DH, DH, Kg[0], w4, lane);
    stage64(Vp + tbase * 64, SEQ, Vg[0], w4, lane);
    __syncthreads();

    for (int i = 0; i < niter; ++i) {
        const int t = tbase + i;
        const int cur = i & 1;
        if (i + 1 < niter) {
            int k1 = (t + 1) * 64;
            stage64(Kp + (size_t)k1 * DH, DH, Kg[cur ^ 1], w4, lane);
            stage64(Vp + k1, SEQ, Vg[cur ^ 1], w4, lane);
        }
        const int k0 = t * 64;
        if (k0 <= wqmax) {
            // S^T = K Q^T with permuted K rows
            f32x4 sf[4][2];
            #pragma unroll
            for (int fj = 0; fj < 4; ++fj) {
                int krow = (fj >> 1) * 32 + krbase + (fj & 1) * 4;
                const u16* kp = Kg[cur] + krow * 64;
                short8 k0f = *(const short8*)(kp + (quad ^ ksig) * 8);
                short8 k1f = *(const short8*)(kp + ((4 + quad) ^ ksig) * 8);
                #pragma unroll
                for (int qa = 0; qa < 2; ++qa) {
                    f32x4 s = (f32x4){0.f, 0.f, 0.f, 0.f};
                    s = __builtin_amdgcn_mfma_f32_16x16x32_bf16(k0f, qf[qa][0], s, 0, 0, 0);
                    s = __builtin_amdgcn_mfma_f32_16x16x32_bf16(k1f, qf[qa][1], s, 0, 0, 0);
                    sf[fj][qa] = s;
                }
            }
            const bool diag = (k0 + 63 > q0 + wq0);
            short8 pA[2][2];
            #pragma unroll
            for (int qa = 0; qa < 2; ++qa) {
                #pragma unroll
                for (int fj = 0; fj < 4; ++fj)
                    #pragma unroll
                    for (int r = 0; r < 4; ++r) {
                        float p = __builtin_amdgcn_exp2f(sf[fj][qa][r]);
                        if (diag) {
                            int key = k0 + (fj >> 1) * 32 + quad * 8 + (fj & 1) * 4 + r;
                            int qg  = q0 + wq0 + qa * 16 + l15;
                            p = (key <= qg) ? p : 0.f;
                        }
                        sf[fj][qa][r] = p;
                    }
                union { uint32_t d[4]; short8 v; } a0, a1;
                a0.d[0] = pktrunc(sf[0][qa][0], sf[0][qa][1]);
                a0.d[1] = pktrunc(sf[0][qa][2], sf[0][qa][3]);
                a0.d[2] = pktrunc(sf[1][qa][0], sf[1][qa][1]);
                a0.d[3] = pktrunc(sf[1][qa][2], sf[1][qa][3]);
                a1.d[0] = pktrunc(sf[2][qa][0], sf[2][qa][1]);
                a1.d[1] = pktrunc(sf[2][qa][2], sf[2][qa][3]);
                a1.d[2] = pktrunc(sf[3][qa][0], sf[3][qa][1]);
                a1.d[3] = pktrunc(sf[3][qa][2], sf[3][qa][3]);
                pA[qa][0] = a0.v;
                pA[qa][1] = a1.v;
                L[qa] = __builtin_amdgcn_mfma_f32_16x16x32_bf16(pA[qa][0], ones, L[qa], 0, 0, 0);
                L[qa] = __builtin_amdgcn_mfma_f32_16x16x32_bf16(pA[qa][1], ones, L[qa], 0, 0, 0);
            }
            #pragma unroll
            for (int fo = 0; fo < 4; ++fo) {
                const u16* vrow = Vg[cur] + (fo * 16 + l15) * 64;
                short8 vb0 = *(const short8*)(vrow + (quad ^ vsig) * 8);
                short8 vb1 = *(const short8*)(vrow + ((4 + quad) ^ vsig) * 8);
                #pragma unroll
                for (int pa = 0; pa < 2; ++pa) {
                    O[pa][fo] = __builtin_amdgcn_mfma_f32_16x16x32_bf16(pA[pa][0], vb0, O[pa][fo], 0, 0, 0);
                    O[pa][fo] = __builtin_amdgcn_mfma_f32_16x16x32_bf16(pA[pa][1], vb1, O[pa][fo], 0, 0, 0);
                }
            }
        }
        __syncthreads();
    }

    // in-block combine: g0 parks O/L in LDS (overlaying K/V, all reads done),
    // g1 adds, normalizes, writes. Osh stride 66 floats -> 2-way banks (free).
    float* Osh = (float*)smem;            // [128][66]
    float* Lsh = Osh + 128 * 66;          // [128]
    if (grp == 0) {
        #pragma unroll
        for (int pa = 0; pa < 2; ++pa) {
            #pragma unroll
            for (int fo = 0; fo < 4; ++fo)
                #pragma unroll
                for (int r = 0; r < 4; ++r)
                    Osh[(wq0 + pa * 16 + quad * 4 + r) * 66 + fo * 16 + l15] = O[pa][fo][r];
            if (l15 == 0) {
                #pragma unroll
                for (int r = 0; r < 4; ++r)
                    Lsh[wq0 + pa * 16 + quad * 4 + r] = L[pa][r];
            }
        }
    }
    __syncthreads();
    if (grp == 1) {
        #pragma unroll
        for (int pa = 0; pa < 2; ++pa) {
            float lt[4];
            #pragma unroll
            for (int r = 0; r < 4; ++r)
                lt[r] = L[pa][r] + Lsh[wq0 + pa * 16 + quad * 4 + r];
            #pragma unroll
            for (int fo = 0; fo < 4; ++fo)
                #pragma unroll
                for (int r = 0; r < 4; ++r) {
                    int q = wq0 + pa * 16 + quad * 4 + r;
                    float o = O[pa][fo][r] + Osh[q * 66 + fo * 16 + l15];
                    out[((size_t)b * SEQ + q0 + q) * 1024 + h * DH + fo * 16 + l15] = o / lt[r];
                }
        }
    }
}

extern "C" void kernel_launch(void* const* d_in, const int* in_sizes, int n_in,
                              void* d_out, int out_size, void* d_ws, size_t ws_size,
                              hipStream_t stream) {
    const float* x  = (const float*)d_in[0];
    const float* Wq = (const float*)d_in[1];
    const float* bq = (const float*)d_in[2];
    const float* Wk = (const float*)d_in[3];
    const float* bk = (const float*)d_in[4];
    const float* Wv = (const float*)d_in[5];
    const float* bv = (const float*)d_in[6];
    float* out = (float*)d_out;

    const size_t NX = (size_t)BATCH * SEQ * D_IN;    // 4M
    const size_t NW = (size_t)3 * D_IN * 1024;       // 3M
    const size_t NP = (size_t)BATCH * NH * SEQ * DH; // 4M
    u16* xb = (u16*)d_ws;
    u16* WT = xb + NX;
    u16* Qb = WT + NW;
    u16* Kb = Qb + NP;
    u16* Vt = Kb + NP;

    prep_kernel<<<4096 + 768, 256, 0, stream>>>(x, Wq, Wk, Wv, xb, WT);
    qkv_gemm_kernel<<<dim3(24, 32), 256, 0, stream>>>(xb, WT, bq, bk, bv, Qb, Kb, Vt);
    flash_mfma_kernel<<<dim3(32, 16), 512, 0, stream>>>(Qb, Kb, Vt, out);
}